// Round 1
// 63.354 us; speedup vs baseline: 1.0029x; 1.0029x over previous
//
#include <hip/hip_runtime.h>
#include <math.h>

#define NG 1024
#define NWAVES 8               // 512 threads
#define IMG_W 256
#define IMG_H 256
#define TILE_W 16
#define TILE_H 8               // 16x8 px tile -> 512 blocks -> 2 blocks/CU
#define NPX (TILE_W * TILE_H)  // 128
#define JITTER 1e-6f
#define L2E 1.4426950408889634f
#define CULL_LOG2_EPS -15.0f   // cull if exact max alpha over tile < 2^-15

__device__ __forceinline__ float fexp2(float x)  { return __builtin_amdgcn_exp2f(x); }
__device__ __forceinline__ float flog2(float x)  { return __builtin_amdgcn_logf(x); }
__device__ __forceinline__ float frcp(float x)   { return __builtin_amdgcn_rcpf(x); }
__device__ __forceinline__ float fexp(float x)   { return fexp2(x * L2E); }
__device__ __forceinline__ float fsigmoid(float x) { return frcp(1.0f + fexp(-x)); }
__device__ __forceinline__ float ftanh(float x) {
    float t = fexp2(2.0f * L2E * x);      // exp(2x)
    return 1.0f - 2.0f * frcp(t + 1.0f);
}

// Fused single kernel. Block = 512 threads = 8 waves, owns one 16x8 tile.
// Grid = 512 blocks -> 2 blocks/CU (launch_bounds(512,4)) = 16 waves/CU,
// double the latency-hiding of the previous 16x16/1-block-per-CU version,
// and the finer y-granularity exact cull cuts gaussian-pixel pairs ~16%.
// Phase 1 (2 rounds of 512): per-thread param compute + EXACT tile cull
//   (concave quadratic max over rect). Survivors compacted IN GAUSSIAN-INDEX
//   ORDER into LDS (ballot + popcount prefix; double-buffered masks).
// Phase 2: wave w composites ordered survivor segment over all 128 px,
//   2 px per lane as a COLUMN (shared x -> 3 FMAs shared per gaussian).
// Phase 3: in-order (A,T) monoid combine across the 8 segments, write out.
__global__ __launch_bounds__(512, 4)
void gs_tiled(const float* __restrict__ means,
              const float* __restrict__ scales,
              const float* __restrict__ thetas,
              const float* __restrict__ opacities,
              float* __restrict__ out) {
    __shared__ float4 s_c0123[NG];                 // (c0,c1,c2,c3)
    __shared__ float2 s_c45[NG];                   // (c4,c5)
    __shared__ unsigned long long s_mask[2][NWAVES];
    __shared__ float2 s_seg[NWAVES][NPX];          // per-wave (acc,T) per px

    int tid  = threadIdx.x;
    int lane = tid & 63;
    int wave = tid >> 6;

    // tile rect in NDC; linspace(-1,1,256) step
    const float step = 2.0f / 255.0f;
    int tx = blockIdx.x & (IMG_W / TILE_W - 1);
    int ty = blockIdx.x >> 4;                      // 0..31
    float rx0 = fmaf((float)(tx * TILE_W), step, -1.0f);
    float ry0 = fmaf((float)(ty * TILE_H), step, -1.0f);
    float rx1 = rx0 + (TILE_W - 1) * step;
    float ry1 = ry0 + (TILE_H - 1) * step;

    // ---- Phase 1: params + exact cull + order-preserving compaction ----
    int nsurv = 0;
    #pragma unroll
    for (int k = 0; k < 2; ++k) {
        int g = k * 512 + tid;
        float2 mn = ((const float2*)means)[g];
        float2 sc = ((const float2*)scales)[g];
        float mx = ftanh(mn.x);
        float my = ftanh(mn.y);
        float s2x = fexp(2.0f * sc.x);             // exp(scales)^2
        float s2y = fexp(2.0f * sc.y);
        // theta = sigmoid(t)*2pi; v_sin/cos take revolutions -> feed sigmoid.
        float rev = fsigmoid(thetas[g]);
        float si = __builtin_amdgcn_sinf(rev);
        float c  = __builtin_amdgcn_cosf(rev);
        float a = c * c * s2x + si * si * s2y + JITTER;
        float b = c * si * (s2x - s2y);
        float d = si * si * s2x + c * c * s2y + JITTER;
        float inv_det = frcp(a * d - b * b);
        float c3 = -0.5f * L2E * d * inv_det;      // P  (< 0)
        float c4 =  L2E * b * inv_det;             // Q
        float c5 = -0.5f * L2E * a * inv_det;      // R  (< 0)
        float l2op = flog2(fsigmoid(opacities[g]));
        float c1 = -(2.0f * c3 * mx + c4 * my);
        float c2 = -(c4 * mx + 2.0f * c5 * my);
        float c0 = c3 * mx * mx + c4 * mx * my + c5 * my * my + l2op;

        // Exact max of concave quadratic e2 over the rect:
        float h3 = frcp(c3) * 0.5f;                // 1/(2c3)
        float h5 = frcp(c5) * 0.5f;                // 1/(2c5)
        // edges x = rx0 / rx1: f(y) = c5 y^2 + (c4 e + c2) y + (...)
        float B0 = fmaf(c4, rx0, c2);
        float C0 = fmaf(rx0, fmaf(c3, rx0, c1), c0);
        float yv0 = fminf(fmaxf(-B0 * h5, ry0), ry1);
        float v0 = fmaf(yv0, fmaf(c5, yv0, B0), C0);
        float B1 = fmaf(c4, rx1, c2);
        float C1 = fmaf(rx1, fmaf(c3, rx1, c1), c0);
        float yv1 = fminf(fmaxf(-B1 * h5, ry0), ry1);
        float v1 = fmaf(yv1, fmaf(c5, yv1, B1), C1);
        // edges y = ry0 / ry1: f(x) = c3 x^2 + (c4 e + c1) x + (...)
        float B2 = fmaf(c4, ry0, c1);
        float C2 = fmaf(ry0, fmaf(c5, ry0, c2), c0);
        float xv2 = fminf(fmaxf(-B2 * h3, rx0), rx1);
        float v2 = fmaf(xv2, fmaf(c3, xv2, B2), C2);
        float B3 = fmaf(c4, ry1, c1);
        float C3 = fmaf(ry1, fmaf(c5, ry1, c2), c0);
        float xv3 = fminf(fmaxf(-B3 * h3, rx0), rx1);
        float v3 = fmaf(xv3, fmaf(c3, xv3, B3), C3);
        float e2max = fmaxf(fmaxf(v0, v1), fmaxf(v2, v3));
        bool inside = (mx >= rx0) & (mx <= rx1) & (my >= ry0) & (my <= ry1);
        e2max = inside ? l2op : e2max;
        bool keep = e2max >= CULL_LOG2_EPS;

        unsigned long long bal = __ballot(keep);
        if (lane == 0) s_mask[k][wave] = bal;
        __syncthreads();   // masks of round k visible to all waves

        // order-preserving position = survivors before me (across 8 waves)
        int pos = nsurv;
        #pragma unroll
        for (int w = 0; w < NWAVES; ++w) {
            unsigned long long m = s_mask[k][w];
            if (w < wave) pos += __popcll(m);
            nsurv += __popcll(m);
        }
        pos += __popcll(bal & ((1ull << lane) - 1ull));

        if (keep) {
            s_c0123[pos] = make_float4(c0, c1, c2, c3);
            s_c45[pos]   = make_float2(c4, c5);
        }
        // rounds write disjoint mask buffers and disjoint param slots:
        // no barrier needed until params are consumed below.
    }
    __syncthreads();       // all param writes landed before phase 2

    // ---- Phase 2: per-wave ordered segment over 128 px (2 px/lane col) ----
    int Ns = nsurv;   // block-uniform
    int sbeg = __builtin_amdgcn_readfirstlane((Ns * wave) >> 3);
    int send = __builtin_amdgcn_readfirstlane((Ns * (wave + 1)) >> 3);

    int col  = lane & 15;          // shared x per lane
    int rowg = lane >> 4;          // lane covers rows rowg*2, rowg*2+1
    float x  = fmaf((float)col, step, rx0);
    float y0 = fmaf((float)(rowg * 2), step, ry0);
    float y1 = y0 + step;

    float acc0 = 0.f, T0 = 1.f, acc1 = 0.f, T1 = 1.f;

    #pragma unroll 4
    for (int i = sbeg; i < send; ++i) {
        float4 q = s_c0123[i];     // broadcast ds_read_b128
        float2 r = s_c45[i];       // broadcast ds_read_b64
        // e2(x,y) = (c3x^2 + c1x + c0) + (c4x + c2)y + c5y^2
        float t1 = fmaf(x, fmaf(q.w, x, q.y), q.x);   // shared over column
        float u  = fmaf(r.x, x, q.z);                 // shared over column
        float e0 = fmaf(y0, fmaf(r.y, y0, u), t1);
        float a0 = fexp2(e0);
        acc0 = fmaf(a0, T0, acc0); T0 = fmaf(-a0, T0, T0);
        float e1 = fmaf(y1, fmaf(r.y, y1, u), t1);
        float a1 = fexp2(e1);
        acc1 = fmaf(a1, T1, acc1); T1 = fmaf(-a1, T1, T1);
    }

    int pxb = rowg * 2 * TILE_W + col;
    s_seg[wave][pxb]          = make_float2(acc0, T0);
    s_seg[wave][pxb + TILE_W] = make_float2(acc1, T1);
    __syncthreads();

    // ---- Phase 3: in-order combine across 8 segments, write out ----
    if (tid < NPX) {
        float A = 0.0f, Tt = 1.0f;
        #pragma unroll
        for (int s = 0; s < NWAVES; ++s) {
            float2 v = s_seg[s][tid];
            A = fmaf(Tt, v.x, A);
            Tt *= v.y;
        }
        int px = tx * TILE_W + (tid & 15);
        int py = ty * TILE_H + (tid >> 4);
        float* o = out + 3 * (py * IMG_W + px);
        o[0] = A;
        o[1] = A;
        o[2] = A;   // bg = (0,0,0)
    }
}

extern "C" void kernel_launch(void* const* d_in, const int* in_sizes, int n_in,
                              void* d_out, int out_size, void* d_ws, size_t ws_size,
                              hipStream_t stream) {
    const float* means     = (const float*)d_in[0];
    const float* scales    = (const float*)d_in[1];
    const float* thetas    = (const float*)d_in[2];
    const float* opacities = (const float*)d_in[3];
    float* out = (float*)d_out;

    gs_tiled<<<dim3((IMG_W / TILE_W) * (IMG_H / TILE_H)), dim3(512), 0, stream>>>(
        means, scales, thetas, opacities, out);
}